// Round 10
// baseline (60.620 us; speedup 1.0000x reference)
//
#include <hip/hip_runtime.h>

using u64 = unsigned long long;

// Fixed problem shape (guarded in the launcher; generic fallback otherwise).
constexpr int Bc = 2, Tc = 8, Fc = 5, Mc = 128, Sc = 128;
constexpr int Np = 65536;         // points per (b,t) slab
constexpr int WPTS = 512;         // points per wave-chunk (8 per lane)
constexpr int NCH = Np / WPTS;    // 128 chunks per slab
constexpr int NR  = NCH / 4;      // 32 rounds (4 waves x 1 chunk per round)

// Largest x with __fsqrt_rn(x) <= r (monotone correctly-rounded sqrt =>
// d2 <= sqrt_ub(r)  <=>  __fsqrt_rn(d2) <= r : the reference predicate, bit-exact).
__device__ __forceinline__ float sqrt_ub(float r) {
    float u = __fmul_rn(r, r);
    if (__fsqrt_rn(u) <= r) {
        while (true) {
            float nu = __uint_as_float(__float_as_uint(u) + 1u);
            if (__fsqrt_rn(nu) <= r) u = nu; else break;
        }
    } else {
        while (__fsqrt_rn(u) > r) u = __uint_as_float(__float_as_uint(u) - 1u);
    }
    return u;
}

__device__ __forceinline__ float box_radius(const float* __restrict__ box) {
    const float hl = __fmul_rn(0.5f, box[3]);
    const float hw = __fmul_rn(0.5f, box[4]);
    return __fmul_rn(__fsqrt_rn(__fadd_rn(__fmul_rn(hl, hl), __fmul_rn(hw, hw))), 1.1f);
}

// Workgroup barrier WITHOUT the vmcnt(0) drain __syncthreads() would emit.
// Only LDS ordering is required across it (the per-wave counts): lgkmcnt(0)
// makes the ds_write visible; global loads stay in flight across s_barrier.
__device__ __forceinline__ void light_barrier() {
    asm volatile("s_waitcnt lgkmcnt(0)" ::: "memory");
    __builtin_amdgcn_s_barrier();
    asm volatile("" ::: "memory");
}

// One block per (b,t,m) box. 4 waves; per round each wave owns one 512-pt
// chunk: count via 8 ballots (masks kept in regs), light barrier, 4-entry
// prefix from LDS, emit from registers at exact slots. Early exit when
// cum >= S (block-uniform). 2-deep register prefetch: round r consumes gen r
// (loaded at r-2) and issues gen r+2 after the exit check, so load latency
// overlaps a full round and is never drained at the barrier.
__global__ __launch_bounds__(256) void k_box(
    const float* __restrict__ points,        // [B,T,N,F]
    const float* __restrict__ rois,          // [B,T,M,7]
    const int*   __restrict__ vlen,          // [B,T,M]
    float*       __restrict__ out)           // [B,M,T,S,F]
{
    const int blk = blockIdx.x;
    const int m  = blk & (Mc - 1);           // 128 consecutive blocks share a slab
    const int bt = blk >> 7;
    const int t = bt & 7, b = bt >> 3;

    // fallback rows (t!=0, vlen==0) recompute the frame-0 pooling exactly
    int t_eff = t;
    if (t != 0 && vlen[bt * Mc + m] == 0) t_eff = 0;
    const int btE = b * Tc + t_eff;

    const float* box = rois + (size_t)(btE * Mc + m) * 7;
    const float cx = box[0], cy = box[1];
    const float T = sqrt_ub(box_radius(box));
    const float* pts = points + (size_t)btE * Np * Fc;
    float* orow = out + (size_t)((b * Mc + m) * Tc + t) * (Sc * Fc);

    __shared__ int wcnt[2][4];

    const int tid = threadIdx.x, lane = tid & 63, wv = tid >> 6;
    const u64 lt = (1ull << lane) - 1ull;

    // generations: px/py = round r, ax/ay = round r+1, fx/fy = round r+2
    float px[8], py[8], ax[8], ay[8];
    {
        const int p0 = wv * WPTS;
        const int p1 = (4 + wv) * WPTS;
        #pragma unroll
        for (int i = 0; i < 8; ++i) {
            const size_t i0 = (size_t)(p0 + i * 64 + lane);
            px[i] = pts[i0 * Fc + 0];
            py[i] = pts[i0 * Fc + 1];
        }
        #pragma unroll
        for (int i = 0; i < 8; ++i) {
            const size_t i1 = (size_t)(p1 + i * 64 + lane);
            ax[i] = pts[i1 * Fc + 0];
            ay[i] = pts[i1 * Fc + 1];
        }
    }

    int cum = 0;
    for (int r = 0; r < NR; ++r) {
        // ---- count my chunk; keep the 8 ballot masks in regs ----
        u64 bal[8];
        int c = 0;
        #pragma unroll
        for (int i = 0; i < 8; ++i) {
            const float dx = __fsub_rn(px[i], cx);
            const float dy = __fsub_rn(py[i], cy);
            const float d2 = __fadd_rn(__fmul_rn(dx, dx), __fmul_rn(dy, dy));
            bal[i] = __ballot(d2 <= T);
            c += (int)__popcll(bal[i]);
        }
        if (lane == 0) wcnt[r & 1][wv] = c;

        light_barrier();                       // no vmcnt drain

        const int c0 = wcnt[r & 1][0], c1 = wcnt[r & 1][1];
        const int c2 = wcnt[r & 1][2], c3 = wcnt[r & 1][3];
        int base = cum;
        if (wv > 0) base += c0;
        if (wv > 1) base += c1;
        if (wv > 2) base += c2;
        const int newcum = cum + c0 + c1 + c2 + c3;

        // ---- issue gen r+2 only if the block will still be running ----
        float fx[8], fy[8];
        if (newcum < Sc && r + 2 < NR) {       // block-uniform condition
            const int pf = ((r + 2) * 4 + wv) * WPTS;
            #pragma unroll
            for (int i = 0; i < 8; ++i) {
                const size_t idx = (size_t)(pf + i * 64 + lane);
                fx[i] = pts[idx * Fc + 0];
                fy[i] = pts[idx * Fc + 1];
            }
        } else {
            #pragma unroll
            for (int i = 0; i < 8; ++i) { fx[i] = 0.0f; fy[i] = 0.0f; }
        }

        // ---- emit winners from registers (wave-uniform skip) ----
        if (base < Sc && c > 0) {
            const int pbase = (r * 4 + wv) * WPTS;
            int sb = base;
            #pragma unroll
            for (int i = 0; i < 8; ++i) {
                if ((bal[i] >> lane) & 1ull) {
                    const int slot = sb + (int)__popcll(bal[i] & lt);
                    if (slot < Sc) {
                        const size_t idx = (size_t)(pbase + i * 64 + lane);
                        float* o = orow + (size_t)slot * Fc;
                        o[0] = px[i]; o[1] = py[i];
                        o[2] = pts[idx * Fc + 2];   // payload lines are cache-hot
                        o[3] = pts[idx * Fc + 3];
                        o[4] = pts[idx * Fc + 4];
                    }
                }
                sb += (int)__popcll(bal[i]);
            }
        }

        cum = newcum;
        if (cum >= Sc) break;                  // block-uniform
        #pragma unroll
        for (int i = 0; i < 8; ++i) {
            px[i] = ax[i]; py[i] = ay[i];
            ax[i] = fx[i]; ay[i] = fy[i];
        }
        // parity double-buffer on wcnt: round r+2's rewrite of wcnt[r&1]
        // happens after barrier r+1, which every wave passes only after its
        // round-r read. safe.
    }

    // ---- zero the tail slots [min(cum,S), S) ----
    const int fill = min(cum, Sc);
    for (int i = fill * Fc + tid; i < Sc * Fc; i += 256) orow[i] = 0.0f;
}

// ---------------- fallback: R2 single-kernel path (shape-generic) ------------
__global__ __launch_bounds__(1024) void vox_pool(
    const float* __restrict__ points, const float* __restrict__ rois,
    const int* __restrict__ valid_length, float* __restrict__ out,
    int N, int M, int S)
{
    const int blk = blockIdx.x;
    const int m = blk % M;
    const int t = (blk / M) % Tc;
    const int b = blk / (M * Tc);
    int t_eff = t;
    if (t != 0 && valid_length[(b * Tc + t) * M + m] == 0) t_eff = 0;
    const float* box = rois + (size_t)((b * Tc + t_eff) * M + m) * 7;
    const float cx = box[0], cy = box[1];
    const float r = box_radius(box);
    const float* pts = points + (size_t)(b * Tc + t_eff) * N * Fc;
    float* o = out + ((size_t)(b * M + m) * Tc + t) * (size_t)S * Fc;
    __shared__ int wcnt[16];
    const int tid = threadIdx.x, lane = tid & 63, wav = tid >> 6;
    const int nthreads = blockDim.x, nwaves = nthreads >> 6;
    int cnt = 0;
    for (int basei = 0; basei < N; basei += nthreads) {
        const int idx = basei + tid;
        bool inside = false;
        if (idx < N) {
            const float dx = __fsub_rn(pts[(size_t)idx * Fc + 0], cx);
            const float dy = __fsub_rn(pts[(size_t)idx * Fc + 1], cy);
            const float d2 = __fadd_rn(__fmul_rn(dx, dx), __fmul_rn(dy, dy));
            inside = (__fsqrt_rn(d2) <= r);
        }
        const unsigned long long bal = __ballot(inside);
        if (lane == 0) wcnt[wav] = __popcll(bal);
        __syncthreads();
        int wave_off = 0, block_tot = 0;
        for (int w = 0; w < nwaves; ++w) {
            const int c = wcnt[w];
            if (w < wav) wave_off += c;
            block_tot += c;
        }
        if (inside) {
            const int slot = cnt + wave_off + (int)__popcll(bal & ((1ull << lane) - 1ull));
            if (slot < S)
                for (int f = 0; f < Fc; ++f)
                    o[(size_t)slot * Fc + f] = pts[(size_t)idx * Fc + f];
        }
        cnt += block_tot;
        __syncthreads();
        if (cnt >= S) break;
    }
    const int filled = cnt < S ? cnt : S;
    for (int s = filled + tid; s < S; s += nthreads)
        for (int f = 0; f < Fc; ++f)
            o[(size_t)s * Fc + f] = 0.0f;
}

extern "C" void kernel_launch(void* const* d_in, const int* in_sizes, int n_in,
                              void* d_out, int out_size, void* d_ws, size_t ws_size,
                              hipStream_t stream) {
    const float* points = (const float*)d_in[0];
    const float* rois   = (const float*)d_in[1];
    const int*   vlen   = (const int*)d_in[2];
    float* out = (float*)d_out;

    const bool fixed =
        in_sizes[0] == Bc * Tc * Np * Fc &&
        in_sizes[1] == Bc * Tc * Mc * 7 &&
        in_sizes[2] == Bc * Tc * Mc &&
        out_size    == Bc * Mc * Tc * Sc * Fc;

    if (fixed) {
        k_box<<<dim3(Bc * Tc * Mc), 256, 0, stream>>>(points, rois, vlen, out);
    } else {
        const int N = in_sizes[0] / (Bc * Tc * Fc);
        const int M = in_sizes[2] / (Bc * Tc);
        const int S = out_size / (Bc * M * Tc * Fc);
        vox_pool<<<dim3(Bc * Tc * M), 1024, 0, stream>>>(points, rois, vlen, out, N, M, S);
    }
}